// Round 1
// baseline (255.186 us; speedup 1.0000x reference)
//
#include <hip/hip_runtime.h>

// Problem constants
#define NB 8
#define NS 1024
#define NE 768
#define NH 12
#define ND 64
#define NM (NB*NS)      // 8192

typedef __attribute__((ext_vector_type(8))) short bf16x8;
typedef __attribute__((ext_vector_type(4))) float f32x4;
typedef const __attribute__((address_space(1))) void gv_t;
typedef __attribute__((address_space(3))) void sv_t;

static __device__ __forceinline__ ushort f2bf(float f) {
  union { float f; unsigned u; } c; c.f = f;
  unsigned u = c.u + 0x7fffu + ((c.u >> 16) & 1u);
  return (ushort)(u >> 16);
}
static __device__ __forceinline__ float bf2f(ushort h) {
  union { unsigned u; float f; } c; c.u = ((unsigned)h) << 16;
  return c.f;
}

// ---------------- f32 -> bf16 conversion ----------------
__global__ void cvt_x(const float* __restrict__ src, ushort* __restrict__ dst) {
  int i = (blockIdx.x * 256 + threadIdx.x) * 4;
  float4 f = *(const float4*)(src + i);
  ushort4 o;
  o.x = f2bf(f.x); o.y = f2bf(f.y); o.z = f2bf(f.z); o.w = f2bf(f.w);
  *(ushort4*)(dst + i) = o;
}

__global__ void cvt_weights(const float* __restrict__ w0, const float* __restrict__ w1,
                            const float* __restrict__ w2, const float* __restrict__ w3,
                            const float* __restrict__ w4,
                            ushort* __restrict__ o0, ushort* __restrict__ o1,
                            ushort* __restrict__ o2, ushort* __restrict__ o3,
                            ushort* __restrict__ o4) {
  int blk = blockIdx.x;
  const float* src; ushort* dst; int idx;
  if (blk < 2304) {
    int ws = blk / 576, b = blk % 576;
    src = (ws == 0) ? w0 : (ws == 1) ? w1 : (ws == 2) ? w2 : w3;
    dst = (ws == 0) ? o0 : (ws == 1) ? o1 : (ws == 2) ? o2 : o3;
    idx = b;
  } else {
    src = w4; dst = o4; idx = blk - 2304;
  }
  int i = (idx * 256 + threadIdx.x) * 4;
  float4 f = *(const float4*)(src + i);
  ushort4 o;
  o.x = f2bf(f.x); o.y = f2bf(f.y); o.z = f2bf(f.z); o.w = f2bf(f.w);
  *(ushort4*)(dst + i) = o;
}

// ---------------- GEMM core: C[128x128] tile of A[M,768] @ B[N,768]^T ----------------
// 256 threads, 4 waves, each wave 64x64 (4x4 frags of 16x16x32 bf16 MFMA)
__device__ __forceinline__ void gemm_core(const ushort* __restrict__ A,
                                          const ushort* __restrict__ Bw,
                                          ushort* As, ushort* Bs,
                                          int bm0, int bn0, f32x4 (&acc)[4][4]) {
  const int tid = threadIdx.x;
  const int w = tid >> 6, lane = tid & 63;
  const int l15 = lane & 15, l4 = lane >> 4;
  const int wm = w >> 1, wn = w & 1;
  const int row = tid >> 2, seg = tid & 3;   // staging: 8-bf16 chunk per lane

  #pragma unroll 1
  for (int kt = 0; kt < 24; ++kt) {
    __syncthreads();
    #pragma unroll
    for (int p = 0; p < 2; ++p) {
      const ushort* ga = A + (size_t)(bm0 + p * 64 + row) * 768 + kt * 32 + seg * 8;
      __builtin_amdgcn_global_load_lds((gv_t*)ga, (sv_t*)(As + (p * 256 + w * 64) * 8), 16, 0, 0);
      const ushort* gb = Bw + (size_t)(bn0 + p * 64 + row) * 768 + kt * 32 + seg * 8;
      __builtin_amdgcn_global_load_lds((gv_t*)gb, (sv_t*)(Bs + (p * 256 + w * 64) * 8), 16, 0, 0);
    }
    __syncthreads();

    bf16x8 af[4], bf[4];
    #pragma unroll
    for (int mi = 0; mi < 4; ++mi)
      af[mi] = *(const bf16x8*)(As + (wm * 64 + mi * 16 + l15) * 32 + l4 * 8);
    #pragma unroll
    for (int ni = 0; ni < 4; ++ni)
      bf[ni] = *(const bf16x8*)(Bs + (wn * 64 + ni * 16 + l15) * 32 + l4 * 8);
    #pragma unroll
    for (int mi = 0; mi < 4; ++mi)
      #pragma unroll
      for (int ni = 0; ni < 4; ++ni)
        acc[mi][ni] = __builtin_amdgcn_mfma_f32_16x16x32_bf16(af[mi], bf[ni], acc[mi][ni], 0, 0, 0);
  }
}

// QKV: one launch; blockIdx.y in [0,18): wsel = y/6 picks W/dst, bn = y%6
__global__ __launch_bounds__(256)
void gemm_qkv(const ushort* __restrict__ A,
              const ushort* __restrict__ B0, const ushort* __restrict__ B1, const ushort* __restrict__ B2,
              ushort* __restrict__ C0, ushort* __restrict__ C1, ushort* __restrict__ C2) {
  __shared__ ushort As[128 * 32];
  __shared__ ushort Bs[128 * 32];
  const int wsel = blockIdx.y / 6;
  const int bn0 = (blockIdx.y % 6) * 128;
  const int bm0 = blockIdx.x * 128;
  const ushort* Bw = (wsel == 0) ? B0 : (wsel == 1) ? B1 : B2;
  ushort* Co = (wsel == 0) ? C0 : (wsel == 1) ? C1 : C2;

  f32x4 acc[4][4];
  #pragma unroll
  for (int i = 0; i < 4; ++i)
    #pragma unroll
    for (int j = 0; j < 4; ++j)
      acc[i][j] = (f32x4){0.f, 0.f, 0.f, 0.f};

  gemm_core(A, Bw, As, Bs, bm0, bn0, acc);

  const int lane = threadIdx.x & 63;
  const int w = threadIdx.x >> 6;
  const int l15 = lane & 15, l4 = lane >> 4;
  const int wm = w >> 1, wn = w & 1;
  #pragma unroll
  for (int mi = 0; mi < 4; ++mi) {
    #pragma unroll
    for (int ni = 0; ni < 4; ++ni) {
      #pragma unroll
      for (int e = 0; e < 4; ++e) {
        int m = bm0 + wm * 64 + mi * 16 + l4 * 4 + e;
        int n = bn0 + wn * 64 + ni * 16 + l15;
        int b = m >> 10, s = m & 1023, h = n >> 6, d = n & 63;
        Co[(size_t)(b * NH + h) * 65536 + (s << 6) + d] = f2bf(acc[mi][ni][e]);
      }
    }
  }
}

// Output projection: y[8192,768] @ Wp^T -> f32 out
__global__ __launch_bounds__(256)
void gemm_proj(const ushort* __restrict__ A, const ushort* __restrict__ Bw,
               float* __restrict__ Cout) {
  __shared__ ushort As[128 * 32];
  __shared__ ushort Bs[128 * 32];
  const int bm0 = blockIdx.x * 128;
  const int bn0 = blockIdx.y * 128;

  f32x4 acc[4][4];
  #pragma unroll
  for (int i = 0; i < 4; ++i)
    #pragma unroll
    for (int j = 0; j < 4; ++j)
      acc[i][j] = (f32x4){0.f, 0.f, 0.f, 0.f};

  gemm_core(A, Bw, As, Bs, bm0, bn0, acc);

  const int lane = threadIdx.x & 63;
  const int w = threadIdx.x >> 6;
  const int l15 = lane & 15, l4 = lane >> 4;
  const int wm = w >> 1, wn = w & 1;
  #pragma unroll
  for (int mi = 0; mi < 4; ++mi) {
    #pragma unroll
    for (int ni = 0; ni < 4; ++ni) {
      #pragma unroll
      for (int e = 0; e < 4; ++e) {
        int m = bm0 + wm * 64 + mi * 16 + l4 * 4 + e;
        int n = bn0 + wn * 64 + ni * 16 + l15;
        Cout[(size_t)m * NE + n] = acc[mi][ni][e];
      }
    }
  }
}

// ---------------- Flash attention with relative-position bias ----------------
// grid (16 qtiles, 96 bh), 256 threads = 4 waves, each wave owns 16 q-rows.
__global__ __launch_bounds__(256)
void attn_kernel(const ushort* __restrict__ q, const ushort* __restrict__ k,
                 const ushort* __restrict__ v, const ushort* __restrict__ pe,
                 ushort* __restrict__ y) {
  __shared__ ushort R_lds[64 * 264];      // rel-pos logits R[i][p], padded stride
  __shared__ ushort K_lds[64 * 72];       // K tile [j][d], padded
  __shared__ ushort Vt_lds[64 * 72];      // V^T tile [d][j], padded
  __shared__ ushort P_lds[4][16 * 72];    // per-wave P relayout C->A frag

  const int tid = threadIdx.x;
  const int w = tid >> 6, lane = tid & 63;
  const int l15 = lane & 15, l4 = lane >> 4;
  const int qt = blockIdx.x, bh = blockIdx.y;
  const size_t base = (size_t)bh * (NS * ND);
  const ushort* qp = q + base;
  const ushort* kp = k + base;
  const ushort* vp = v + base;

  // Q fragments (A-operand): row = l15 within wave's 16 rows, k = d
  const int qrow_g = qt * 64 + w * 16 + l15;
  const bf16x8 aq0 = *(const bf16x8*)(qp + qrow_g * 64 + l4 * 8);
  const bf16x8 aq1 = *(const bf16x8*)(qp + qrow_g * 64 + 32 + l4 * 8);

  // R tile: R[r][p] = q_r . pe[p]  (wave computes its own 16 rows)
  #pragma unroll 4
  for (int ct = 0; ct < 16; ++ct) {
    const int pcol = ct * 16 + l15;
    bf16x8 b0 = *(const bf16x8*)(pe + pcol * 64 + l4 * 8);
    bf16x8 b1 = *(const bf16x8*)(pe + pcol * 64 + 32 + l4 * 8);
    f32x4 r = {0.f, 0.f, 0.f, 0.f};
    r = __builtin_amdgcn_mfma_f32_16x16x32_bf16(aq0, b0, r, 0, 0, 0);
    r = __builtin_amdgcn_mfma_f32_16x16x32_bf16(aq1, b1, r, 0, 0, 0);
    const int rr = w * 16 + l4 * 4;
    #pragma unroll
    for (int e = 0; e < 4; ++e)
      R_lds[(rr + e) * 264 + pcol] = f2bf(r[e]);
  }

  float m_run[4], l_run[4];
  f32x4 o[4];
  #pragma unroll
  for (int e = 0; e < 4; ++e) { m_run[e] = -1e30f; l_run[e] = 0.f; }
  #pragma unroll
  for (int ct = 0; ct < 4; ++ct) o[ct] = (f32x4){0.f, 0.f, 0.f, 0.f};

  const float SCL = 0.125f * 1.44269504088896f;  // 1/sqrt(64) * log2(e)

  for (int kt = 0; kt < 16; ++kt) {
    __syncthreads();   // previous tile's LDS reads done
    // stage K tile [64][64] (linear-ish, padded 72) and V^T tile
    #pragma unroll
    for (int p = 0; p < 2; ++p) {
      const int li = p * 256 + tid;
      const int j = li >> 3, seg = li & 7;
      uint4 kvv = *(const uint4*)(kp + (kt * 64 + j) * 64 + seg * 8);
      *(uint4*)(K_lds + j * 72 + seg * 8) = kvv;
      uint4 vvv = *(const uint4*)(vp + (kt * 64 + j) * 64 + seg * 8);
      const ushort* pv8 = (const ushort*)&vvv;
      #pragma unroll
      for (int e = 0; e < 8; ++e)
        Vt_lds[(seg * 8 + e) * 72 + j] = pv8[e];
    }
    __syncthreads();

    // QK^T: 16 q-rows x 64 keys per wave
    f32x4 sfr[4];
    #pragma unroll
    for (int ct = 0; ct < 4; ++ct) {
      bf16x8 bk0 = *(const bf16x8*)(K_lds + (ct * 16 + l15) * 72 + l4 * 8);
      bf16x8 bk1 = *(const bf16x8*)(K_lds + (ct * 16 + l15) * 72 + 32 + l4 * 8);
      f32x4 a = {0.f, 0.f, 0.f, 0.f};
      a = __builtin_amdgcn_mfma_f32_16x16x32_bf16(aq0, bk0, a, 0, 0, 0);
      a = __builtin_amdgcn_mfma_f32_16x16x32_bf16(aq1, bk1, a, 0, 0, 0);
      sfr[ct] = a;
    }

    // logits (log2 domain) + rel-pos bias
    float lg[4][4], mx[4];
    #pragma unroll
    for (int e = 0; e < 4; ++e) mx[e] = -1e30f;
    const int i_base = qt * 64 + w * 16 + l4 * 4;
    #pragma unroll
    for (int ct = 0; ct < 4; ++ct) {
      const int j_g = kt * 64 + ct * 16 + l15;
      #pragma unroll
      for (int e = 0; e < 4; ++e) {
        int rel = j_g - (i_base + e);
        rel = rel < -128 ? -128 : (rel > 127 ? 127 : rel);
        const float pos = bf2f(R_lds[(w * 16 + l4 * 4 + e) * 264 + (rel & 255)]);
        const float t = (sfr[ct][e] + pos) * SCL;
        lg[ct][e] = t;
        mx[e] = fmaxf(mx[e], t);
      }
    }
    #pragma unroll
    for (int d = 1; d < 16; d <<= 1)
      #pragma unroll
      for (int e = 0; e < 4; ++e)
        mx[e] = fmaxf(mx[e], __shfl_xor(mx[e], d));

    float sc[4], rs[4];
    #pragma unroll
    for (int e = 0; e < 4; ++e) {
      const float mn = fmaxf(m_run[e], mx[e]);
      sc[e] = exp2f(m_run[e] - mn);
      m_run[e] = mn;
      rs[e] = 0.f;
    }
    float pw[4][4];
    #pragma unroll
    for (int ct = 0; ct < 4; ++ct)
      #pragma unroll
      for (int e = 0; e < 4; ++e) {
        const float p = exp2f(lg[ct][e] - m_run[e]);
        pw[ct][e] = p;
        rs[e] += p;
      }
    #pragma unroll
    for (int d = 1; d < 16; d <<= 1)
      #pragma unroll
      for (int e = 0; e < 4; ++e)
        rs[e] += __shfl_xor(rs[e], d);
    #pragma unroll
    for (int e = 0; e < 4; ++e)
      l_run[e] = l_run[e] * sc[e] + rs[e];
    #pragma unroll
    for (int ct = 0; ct < 4; ++ct)
      #pragma unroll
      for (int e = 0; e < 4; ++e)
        o[ct][e] *= sc[e];

    // P: C-frag layout -> A-frag layout through wave-private LDS
    #pragma unroll
    for (int ct = 0; ct < 4; ++ct)
      #pragma unroll
      for (int e = 0; e < 4; ++e)
        P_lds[w][(l4 * 4 + e) * 72 + ct * 16 + l15] = f2bf(pw[ct][e]);

    const bf16x8 pa0 = *(const bf16x8*)(&P_lds[w][l15 * 72 + l4 * 8]);
    const bf16x8 pa1 = *(const bf16x8*)(&P_lds[w][l15 * 72 + 32 + l4 * 8]);
    #pragma unroll
    for (int ct = 0; ct < 4; ++ct) {
      bf16x8 bv0 = *(const bf16x8*)(Vt_lds + (ct * 16 + l15) * 72 + l4 * 8);
      bf16x8 bv1 = *(const bf16x8*)(Vt_lds + (ct * 16 + l15) * 72 + 32 + l4 * 8);
      o[ct] = __builtin_amdgcn_mfma_f32_16x16x32_bf16(pa0, bv0, o[ct], 0, 0, 0);
      o[ct] = __builtin_amdgcn_mfma_f32_16x16x32_bf16(pa1, bv1, o[ct], 0, 0, 0);
    }
  }

  // normalize and write y[b, s, h*64+d] bf16
  const int b = bh / NH, h = bh % NH;
  #pragma unroll
  for (int ct = 0; ct < 4; ++ct) {
    #pragma unroll
    for (int e = 0; e < 4; ++e) {
      const int s_g = qt * 64 + w * 16 + l4 * 4 + e;
      const int d = ct * 16 + l15;
      const float val = o[ct][e] / l_run[e];
      y[(size_t)(b * NS + s_g) * NE + h * 64 + d] = f2bf(val);
    }
  }
}

// ---------------- launch ----------------
extern "C" void kernel_launch(void* const* d_in, const int* in_sizes, int n_in,
                              void* d_out, int out_size, void* d_ws, size_t ws_size,
                              hipStream_t stream) {
  const float* x  = (const float*)d_in[0];
  const float* Wq = (const float*)d_in[1];
  const float* Wk = (const float*)d_in[2];
  const float* Wv = (const float*)d_in[3];
  const float* Wp = (const float*)d_in[4];
  const float* pe = (const float*)d_in[5];

  ushort* ws  = (ushort*)d_ws;
  ushort* xb  = ws;                    // 6291456
  ushort* wqb = xb  + 6291456;         // 589824
  ushort* wkb = wqb + 589824;
  ushort* wvb = wkb + 589824;
  ushort* wpb = wvb + 589824;
  ushort* peb = wpb + 589824;          // 16384
  ushort* qb  = peb + 16384;           // 6291456
  ushort* kb  = qb  + 6291456;
  ushort* vb  = kb  + 6291456;
  ushort* yb  = vb  + 6291456;

  cvt_x<<<dim3(6144), dim3(256), 0, stream>>>(x, xb);
  cvt_weights<<<dim3(2320), dim3(256), 0, stream>>>(Wq, Wk, Wv, Wp, pe,
                                                    wqb, wkb, wvb, wpb, peb);
  gemm_qkv<<<dim3(64, 18), dim3(256), 0, stream>>>(xb, wqb, wkb, wvb, qb, kb, vb);
  attn_kernel<<<dim3(16, 96), dim3(256), 0, stream>>>(qb, kb, vb, peb, yb);
  gemm_proj<<<dim3(64, 6), dim3(256), 0, stream>>>(yb, wpb, (float*)d_out);
}

// Round 2
// 200.701 us; speedup vs baseline: 1.2715x; 1.2715x over previous
//
#include <hip/hip_runtime.h>

// Problem constants
#define NB 8
#define NS 1024
#define NE 768
#define NH 12
#define ND 64

typedef __attribute__((ext_vector_type(8))) short bf16x8;
typedef __attribute__((ext_vector_type(4))) float f32x4;
typedef __attribute__((ext_vector_type(16))) float f32x16;
typedef const __attribute__((address_space(1))) void gv_t;
typedef __attribute__((address_space(3))) void sv_t;

static __device__ __forceinline__ ushort f2bf(float f) {
  union { float f; unsigned u; } c; c.f = f;
  unsigned u = c.u + 0x7fffu + ((c.u >> 16) & 1u);
  return (ushort)(u >> 16);
}
static __device__ __forceinline__ float bf2f(ushort h) {
  union { unsigned u; float f; } c; c.u = ((unsigned)h) << 16;
  return c.f;
}
static __device__ __forceinline__ uint pk_bf16(float lo, float hi) {
  uint r;
  asm("v_cvt_pk_bf16_f32 %0, %1, %2" : "=v"(r) : "v"(lo), "v"(hi));
  return r;
}

// ---------------- f32 -> bf16 conversion ----------------
__global__ void cvt_x(const float* __restrict__ src, ushort* __restrict__ dst) {
  int i = (blockIdx.x * 256 + threadIdx.x) * 4;
  float4 f = *(const float4*)(src + i);
  ushort4 o;
  o.x = f2bf(f.x); o.y = f2bf(f.y); o.z = f2bf(f.z); o.w = f2bf(f.w);
  *(ushort4*)(dst + i) = o;
}

__global__ void cvt_weights(const float* __restrict__ w0, const float* __restrict__ w1,
                            const float* __restrict__ w2, const float* __restrict__ w3,
                            const float* __restrict__ w4,
                            ushort* __restrict__ o0, ushort* __restrict__ o1,
                            ushort* __restrict__ o2, ushort* __restrict__ o3,
                            ushort* __restrict__ o4) {
  int blk = blockIdx.x;
  const float* src; ushort* dst; int idx;
  if (blk < 2304) {
    int ws = blk / 576, b = blk % 576;
    src = (ws == 0) ? w0 : (ws == 1) ? w1 : (ws == 2) ? w2 : w3;
    dst = (ws == 0) ? o0 : (ws == 1) ? o1 : (ws == 2) ? o2 : o3;
    idx = b;
  } else {
    src = w4; dst = o4; idx = blk - 2304;
  }
  int i = (idx * 256 + threadIdx.x) * 4;
  float4 f = *(const float4*)(src + i);
  ushort4 o;
  o.x = f2bf(f.x); o.y = f2bf(f.y); o.z = f2bf(f.z); o.w = f2bf(f.w);
  *(ushort4*)(dst + i) = o;
}

// ---------------- GEMM core: C[128x128] tile of A[M,768] @ B[N,768]^T ----------------
__device__ __forceinline__ void gemm_core(const ushort* __restrict__ A,
                                          const ushort* __restrict__ Bw,
                                          ushort* As, ushort* Bs,
                                          int bm0, int bn0, f32x4 (&acc)[4][4]) {
  const int tid = threadIdx.x;
  const int w = tid >> 6, lane = tid & 63;
  const int l15 = lane & 15, l4 = lane >> 4;
  const int wm = w >> 1, wn = w & 1;
  const int row = tid >> 2, seg = tid & 3;

  #pragma unroll 1
  for (int kt = 0; kt < 24; ++kt) {
    __syncthreads();
    #pragma unroll
    for (int p = 0; p < 2; ++p) {
      const ushort* ga = A + (size_t)(bm0 + p * 64 + row) * 768 + kt * 32 + seg * 8;
      __builtin_amdgcn_global_load_lds((gv_t*)ga, (sv_t*)(As + (p * 256 + w * 64) * 8), 16, 0, 0);
      const ushort* gb = Bw + (size_t)(bn0 + p * 64 + row) * 768 + kt * 32 + seg * 8;
      __builtin_amdgcn_global_load_lds((gv_t*)gb, (sv_t*)(Bs + (p * 256 + w * 64) * 8), 16, 0, 0);
    }
    __syncthreads();

    bf16x8 af[4], bf[4];
    #pragma unroll
    for (int mi = 0; mi < 4; ++mi)
      af[mi] = *(const bf16x8*)(As + (wm * 64 + mi * 16 + l15) * 32 + l4 * 8);
    #pragma unroll
    for (int ni = 0; ni < 4; ++ni)
      bf[ni] = *(const bf16x8*)(Bs + (wn * 64 + ni * 16 + l15) * 32 + l4 * 8);
    #pragma unroll
    for (int mi = 0; mi < 4; ++mi)
      #pragma unroll
      for (int ni = 0; ni < 4; ++ni)
        acc[mi][ni] = __builtin_amdgcn_mfma_f32_16x16x32_bf16(af[mi], bf[ni], acc[mi][ni], 0, 0, 0);
  }
}

// QKV: blockIdx.y in [0,18): wsel = y/6 picks W/dst, bn = y%6
// q,k written [bh][s][d]; v written TRANSPOSED [bh][d][s]
__global__ __launch_bounds__(256)
void gemm_qkv(const ushort* __restrict__ A,
              const ushort* __restrict__ B0, const ushort* __restrict__ B1, const ushort* __restrict__ B2,
              ushort* __restrict__ C0, ushort* __restrict__ C1, ushort* __restrict__ C2) {
  __shared__ ushort As[128 * 32];
  __shared__ ushort Bs[128 * 32];
  const int wsel = blockIdx.y / 6;
  const int bn0 = (blockIdx.y % 6) * 128;
  const int bm0 = blockIdx.x * 128;
  const ushort* Bw = (wsel == 0) ? B0 : (wsel == 1) ? B1 : B2;
  ushort* Co = (wsel == 0) ? C0 : (wsel == 1) ? C1 : C2;

  f32x4 acc[4][4];
  #pragma unroll
  for (int i = 0; i < 4; ++i)
    #pragma unroll
    for (int j = 0; j < 4; ++j)
      acc[i][j] = (f32x4){0.f, 0.f, 0.f, 0.f};

  gemm_core(A, Bw, As, Bs, bm0, bn0, acc);

  const int lane = threadIdx.x & 63;
  const int w = threadIdx.x >> 6;
  const int l15 = lane & 15, l4 = lane >> 4;
  const int wm = w >> 1, wn = w & 1;
  #pragma unroll
  for (int mi = 0; mi < 4; ++mi) {
    #pragma unroll
    for (int ni = 0; ni < 4; ++ni) {
      #pragma unroll
      for (int e = 0; e < 4; ++e) {
        int m = bm0 + wm * 64 + mi * 16 + l4 * 4 + e;
        int n = bn0 + wn * 64 + ni * 16 + l15;
        int b = m >> 10, s = m & 1023, h = n >> 6, d = n & 63;
        if (wsel == 2)
          Co[((size_t)(b * NH + h) * 64 + d) * 1024 + s] = f2bf(acc[mi][ni][e]);
        else
          Co[(size_t)(b * NH + h) * 65536 + (s << 6) + d] = f2bf(acc[mi][ni][e]);
      }
    }
  }
}

// Output projection: y[8192,768] @ Wp^T -> f32 out
__global__ __launch_bounds__(256)
void gemm_proj(const ushort* __restrict__ A, const ushort* __restrict__ Bw,
               float* __restrict__ Cout) {
  __shared__ ushort As[128 * 32];
  __shared__ ushort Bs[128 * 32];
  const int bm0 = blockIdx.x * 128;
  const int bn0 = blockIdx.y * 128;

  f32x4 acc[4][4];
  #pragma unroll
  for (int i = 0; i < 4; ++i)
    #pragma unroll
    for (int j = 0; j < 4; ++j)
      acc[i][j] = (f32x4){0.f, 0.f, 0.f, 0.f};

  gemm_core(A, Bw, As, Bs, bm0, bn0, acc);

  const int lane = threadIdx.x & 63;
  const int w = threadIdx.x >> 6;
  const int l15 = lane & 15, l4 = lane >> 4;
  const int wm = w >> 1, wn = w & 1;
  #pragma unroll
  for (int mi = 0; mi < 4; ++mi) {
    #pragma unroll
    for (int ni = 0; ni < 4; ++ni) {
      #pragma unroll
      for (int e = 0; e < 4; ++e) {
        int m = bm0 + wm * 64 + mi * 16 + l4 * 4 + e;
        int n = bn0 + wn * 64 + ni * 16 + l15;
        Cout[(size_t)m * NE + n] = acc[mi][ni][e];
      }
    }
  }
}

// ---------------- Attention: swapped-operand flash with rel-pos bias ----------------
// grid 3072 = 96 bh * 32 q-blocks of 32 rows. 4 waves split k (256 keys each).
// All MFMA operands loaded directly from global (L2). LDS: R bias table + merge.
__global__ __launch_bounds__(256, 3)
void attn_kernel(const ushort* __restrict__ q, const ushort* __restrict__ k,
                 const ushort* __restrict__ vt, const ushort* __restrict__ pe,
                 ushort* __restrict__ y) {
  __shared__ __align__(16) char smem[33792];
  ushort* Rl = (ushort*)smem;              // [32][264] bf16, k-loop phase
  float* OL  = (float*)smem;               // [4][64][32] f32, merge phase (aliased)
  float* ML  = (float*)(smem + 32768);     // [4][2][32] m,l per wave

  const int tid = threadIdx.x;
  const int w = tid >> 6, lane = tid & 63;
  const int il = lane & 31;
  const int hb = lane >> 5;
  const int hi8 = hb * 8;
  const int half4 = hb * 4;

  // XCD-grouping swizzle: blocks sharing one head's K/V land on one XCD
  const int bid = blockIdx.x;
  const int swz = (bid & 7) * 384 + (bid >> 3);
  const int bh = swz >> 5;
  const int q0 = (swz & 31) * 32;

  const ushort* qp = q + (size_t)bh * 65536;
  const ushort* kp = k + (size_t)bh * 65536;
  const ushort* vp = vt + (size_t)bh * 65536;

  // Q fragments: lane holds row q0+il, d = ks*16 + hi8 + [0,8)
  bf16x8 qf[4];
  #pragma unroll
  for (int ks = 0; ks < 4; ++ks)
    qf[ks] = *(const bf16x8*)(qp + (q0 + il) * 64 + ks * 16 + hi8);

  // R phase: R[i][p] = q_i . pe[p]; each wave computes 2 p-blocks of 32
  #pragma unroll
  for (int pb = 0; pb < 2; ++pb) {
    const int pc0 = (w * 2 + pb) * 32;
    f32x16 r;
    #pragma unroll
    for (int i = 0; i < 16; ++i) r[i] = 0.f;
    #pragma unroll
    for (int ks = 0; ks < 4; ++ks) {
      bf16x8 pf = *(const bf16x8*)(pe + (pc0 + il) * 64 + ks * 16 + hi8);
      r = __builtin_amdgcn_mfma_f32_32x32x16_bf16(qf[ks], pf, r, 0, 0, 0);
    }
    #pragma unroll
    for (int i = 0; i < 16; ++i) {
      const int rr = (i & 3) + 8 * (i >> 2) + half4;
      Rl[rr * 264 + pc0 + il] = f2bf(r[i]);
    }
  }
  __syncthreads();

  const float c_lo = bf2f(Rl[il * 264 + 128]);   // clamp(-128) % 256 = 128
  const float c_hi = bf2f(Rl[il * 264 + 127]);
  const int iq = q0 + il;
  const float SCL = 0.125f * 1.44269504088896f;  // 1/sqrt(64) * log2(e)

  float m_run = -1e30f, l_run = 0.f;
  f32x16 o0, o1;
  #pragma unroll
  for (int i = 0; i < 16; ++i) { o0[i] = 0.f; o1[i] = 0.f; }

  // k-loop: wave w covers keys [w*256, w*256+256), 8 chunks of 32
  #pragma unroll 1
  for (int c = 0; c < 8; ++c) {
    const int jb = w * 256 + c * 32;

    // QK^T (swapped): S^T[j][i], lane holds col i=il, 16 j-rows
    f32x16 s;
    #pragma unroll
    for (int i = 0; i < 16; ++i) s[i] = 0.f;
    #pragma unroll
    for (int ks = 0; ks < 4; ++ks) {
      bf16x8 kf = *(const bf16x8*)(kp + (jb + il) * 64 + ks * 16 + hi8);
      s = __builtin_amdgcn_mfma_f32_32x32x16_bf16(kf, qf[ks], s, 0, 0, 0);
    }

    // V^T fragments (issue loads early; latency hides under softmax VALU)
    const bf16x8 vf00 = *(const bf16x8*)(vp + il * 1024 + jb + hi8);
    const bf16x8 vf01 = *(const bf16x8*)(vp + il * 1024 + jb + 16 + hi8);
    const bf16x8 vf10 = *(const bf16x8*)(vp + (32 + il) * 1024 + jb + hi8);
    const bf16x8 vf11 = *(const bf16x8*)(vp + (32 + il) * 1024 + jb + 16 + hi8);

    // bias + scale (log2 domain)
    const int dlt = jb - q0;
    float t[16];
    if (dlt <= -160 || dlt >= 160) {
      // fully clamped tile: per-row constant bias
      const float cv = (dlt < 0) ? c_lo : c_hi;
      #pragma unroll
      for (int i = 0; i < 16; ++i) t[i] = (s[i] + cv) * SCL;
    } else {
      #pragma unroll
      for (int i = 0; i < 16; ++i) {
        const int rr = (i & 3) + 8 * (i >> 2) + half4;
        int rel = jb + rr - iq;
        rel = rel < -128 ? -128 : (rel > 127 ? 127 : rel);
        t[i] = (s[i] + bf2f(Rl[il * 264 + (rel & 255)])) * SCL;
      }
    }

    // online softmax, lane-local (q per lane); halves stay consistent via xor32
    float cmax = t[0];
    #pragma unroll
    for (int i = 1; i < 16; ++i) cmax = fmaxf(cmax, t[i]);
    cmax = fmaxf(cmax, __shfl_xor(cmax, 32));
    const float m_new = fmaxf(m_run, cmax);
    if (m_new > m_run + 8.f) {     // defer-max threshold (T13)
      const float sc = exp2f(m_run - m_new);
      l_run *= sc;
      m_run = m_new;
      #pragma unroll
      for (int i = 0; i < 16; ++i) { o0[i] *= sc; o1[i] *= sc; }
    }
    float p[16], ls = 0.f;
    #pragma unroll
    for (int i = 0; i < 16; ++i) { p[i] = exp2f(t[i] - m_run); ls += p[i]; }
    ls += __shfl_xor(ls, 32);
    l_run += ls;

    // pack P -> bf16 B-fragments in registers (cvt_pk + xor32 exchange)
    const uint cA = pk_bf16(p[0],  p[1]);
    const uint cB = pk_bf16(p[2],  p[3]);
    const uint cC = pk_bf16(p[4],  p[5]);
    const uint cD = pk_bf16(p[6],  p[7]);
    const uint cE = pk_bf16(p[8],  p[9]);
    const uint cF = pk_bf16(p[10], p[11]);
    const uint cG = pk_bf16(p[12], p[13]);
    const uint cH = pk_bf16(p[14], p[15]);
    const uint xA = __shfl_xor(cA, 32);
    const uint xB = __shfl_xor(cB, 32);
    const uint xC = __shfl_xor(cC, 32);
    const uint xD = __shfl_xor(cD, 32);
    const uint xE = __shfl_xor(cE, 32);
    const uint xF = __shfl_xor(cF, 32);
    const uint xG = __shfl_xor(cG, 32);
    const uint xH = __shfl_xor(cH, 32);
    union FU { bf16x8 v; uint u[4]; } f0, f1;
    if (hb == 0) {
      f0.u[0] = cA; f0.u[1] = cB; f0.u[2] = xA; f0.u[3] = xB;
      f1.u[0] = cE; f1.u[1] = cF; f1.u[2] = xE; f1.u[3] = xF;
    } else {
      f0.u[0] = xC; f0.u[1] = xD; f0.u[2] = cC; f0.u[3] = cD;
      f1.u[0] = xG; f1.u[1] = xH; f1.u[2] = cG; f1.u[3] = cH;
    }

    // PV: O^T[d][i] += V^T[d][k] P^T[k][i]
    o0 = __builtin_amdgcn_mfma_f32_32x32x16_bf16(vf00, f0.v, o0, 0, 0, 0);
    o0 = __builtin_amdgcn_mfma_f32_32x32x16_bf16(vf01, f1.v, o0, 0, 0, 0);
    o1 = __builtin_amdgcn_mfma_f32_32x32x16_bf16(vf10, f0.v, o1, 0, 0, 0);
    o1 = __builtin_amdgcn_mfma_f32_32x32x16_bf16(vf11, f1.v, o1, 0, 0, 0);
  }

  __syncthreads();   // all waves done reading Rl; safe to alias with OL
  #pragma unroll
  for (int i = 0; i < 16; ++i) {
    const int rr = (i & 3) + 8 * (i >> 2) + half4;
    OL[(w * 64 + rr) * 32 + il] = o0[i];
    OL[(w * 64 + 32 + rr) * 32 + il] = o1[i];
  }
  if (hb == 0) {
    ML[(w * 2) * 32 + il] = m_run;
    ML[(w * 2 + 1) * 32 + il] = l_run;
  }
  __syncthreads();

  // flash merge across 4 waves + write y[b, s, h*64+d] bf16
  const int mq = tid & 31;
  const int d0 = (tid >> 5) * 8;
  float mw[4], lw[4];
  #pragma unroll
  for (int wv = 0; wv < 4; ++wv) {
    mw[wv] = ML[(wv * 2) * 32 + mq];
    lw[wv] = ML[(wv * 2 + 1) * 32 + mq];
  }
  float ms = fmaxf(fmaxf(mw[0], mw[1]), fmaxf(mw[2], mw[3]));
  float cw[4], lst = 0.f;
  #pragma unroll
  for (int wv = 0; wv < 4; ++wv) { cw[wv] = exp2f(mw[wv] - ms); lst += cw[wv] * lw[wv]; }
  const float inv = 1.f / lst;
  union OU { bf16x8 v; ushort s[8]; } ou;
  #pragma unroll
  for (int e = 0; e < 8; ++e) {
    float acc = 0.f;
    #pragma unroll
    for (int wv = 0; wv < 4; ++wv)
      acc += cw[wv] * OL[(wv * 64 + d0 + e) * 32 + mq];
    ou.s[e] = f2bf(acc * inv);
  }
  const int b = bh / NH, h = bh % NH;
  *(bf16x8*)(y + ((size_t)(b * NS + q0 + mq)) * NE + h * 64 + d0) = ou.v;
}

// ---------------- launch ----------------
extern "C" void kernel_launch(void* const* d_in, const int* in_sizes, int n_in,
                              void* d_out, int out_size, void* d_ws, size_t ws_size,
                              hipStream_t stream) {
  const float* x  = (const float*)d_in[0];
  const float* Wq = (const float*)d_in[1];
  const float* Wk = (const float*)d_in[2];
  const float* Wv = (const float*)d_in[3];
  const float* Wp = (const float*)d_in[4];
  const float* pe = (const float*)d_in[5];

  ushort* ws  = (ushort*)d_ws;
  ushort* xb  = ws;                    // 6291456
  ushort* wqb = xb  + 6291456;         // 589824
  ushort* wkb = wqb + 589824;
  ushort* wvb = wkb + 589824;
  ushort* wpb = wvb + 589824;
  ushort* peb = wpb + 589824;          // 16384
  ushort* qb  = peb + 16384;           // 6291456
  ushort* kb  = qb  + 6291456;
  ushort* vtb = kb  + 6291456;         // V^T [bh][d][s]
  ushort* yb  = vtb + 6291456;

  cvt_x<<<dim3(6144), dim3(256), 0, stream>>>(x, xb);
  cvt_weights<<<dim3(2320), dim3(256), 0, stream>>>(Wq, Wk, Wv, Wp, pe,
                                                    wqb, wkb, wvb, wpb, peb);
  gemm_qkv<<<dim3(64, 18), dim3(256), 0, stream>>>(xb, wqb, wkb, wvb, qb, kb, vtb);
  attn_kernel<<<dim3(3072), dim3(256), 0, stream>>>(qb, kb, vtb, peb, yb);
  gemm_proj<<<dim3(64, 6), dim3(256), 0, stream>>>(yb, wpb, (float*)d_out);
}